// Round 1
// baseline (497.861 us; speedup 1.0000x reference)
//
#include <hip/hip_runtime.h>

#define NN   4096
#define FIN  512
#define FOUT 64
#define NH   8
#define ALPHA 0.2f

// ---------------------------------------------------------------------------
// K1: Wh[h][n][o] = sum_k x[n][k] * W[h][k][o]
// grid (NN/64, NH), 256 threads. 64x64 output tile, BK=16, 4x4 per thread.
// ---------------------------------------------------------------------------
__global__ __launch_bounds__(256) void k1_wh(const float* __restrict__ x,
                                             const float* __restrict__ W,
                                             float* __restrict__ Wh) {
    __shared__ float As[16][68];   // [k][row]
    __shared__ float Bs[16][68];   // [k][o]
    const int t    = threadIdx.x;
    const int h    = blockIdx.y;
    const int row0 = blockIdx.x * 64;
    const int tr = t >> 4, tc = t & 15;
    const int ar = t >> 2, ak = t & 3;    // A staging: row 0..63, k-quad 0..3
    const int bk = t >> 4, bo = t & 15;   // B staging: k 0..15, o-quad 0..15
    const float* WH = W + (size_t)h * FIN * FOUT;
    float acc[4][4] = {};

    for (int k0 = 0; k0 < FIN; k0 += 16) {
        __syncthreads();
        float4 av = *(const float4*)&x[(size_t)(row0 + ar) * FIN + k0 + ak * 4];
        As[ak*4+0][ar] = av.x; As[ak*4+1][ar] = av.y;
        As[ak*4+2][ar] = av.z; As[ak*4+3][ar] = av.w;
        *(float4*)&Bs[bk][bo*4] =
            *(const float4*)&WH[(size_t)(k0 + bk) * FOUT + bo*4];
        __syncthreads();
        #pragma unroll
        for (int kk = 0; kk < 16; ++kk) {
            float4 a4 = *(const float4*)&As[kk][tr*4];
            float4 b4 = *(const float4*)&Bs[kk][tc*4];
            float a[4] = {a4.x, a4.y, a4.z, a4.w};
            float b[4] = {b4.x, b4.y, b4.z, b4.w};
            #pragma unroll
            for (int i = 0; i < 4; ++i)
                #pragma unroll
                for (int j = 0; j < 4; ++j)
                    acc[i][j] = fmaf(a[i], b[j], acc[i][j]);
        }
    }
    float* outp = Wh + (size_t)h * NN * FOUT;
    #pragma unroll
    for (int i = 0; i < 4; ++i) {
        float4 v = {acc[i][0], acc[i][1], acc[i][2], acc[i][3]};
        *(float4*)&outp[(size_t)(row0 + tr*4 + i) * FOUT + tc*4] = v;
    }
}

// ---------------------------------------------------------------------------
// K2: f1[h][n] = sum_o Wh[h][n][o]*a[h][o]; f2 with a[h][FOUT+o].
// One 64-lane group per (h,n). grid NH*NN/4, 256 threads.
// ---------------------------------------------------------------------------
__global__ __launch_bounds__(256) void k2_f12(const float* __restrict__ Wh,
                                              const float* __restrict__ a,
                                              float* __restrict__ f1,
                                              float* __restrict__ f2) {
    const int id   = blockIdx.x * 4 + (threadIdx.x >> 6);  // (h*NN+n) flat
    const int lane = threadIdx.x & 63;
    const int h    = id >> 12;                              // id / 4096
    float v  = Wh[(size_t)id * FOUT + lane];
    float s1 = v * a[h * 2 * FOUT + lane];
    float s2 = v * a[h * 2 * FOUT + FOUT + lane];
    #pragma unroll
    for (int m = 32; m; m >>= 1) {
        s1 += __shfl_xor(s1, m);
        s2 += __shfl_xor(s2, m);
    }
    if (lane == 0) { f1[id] = s1; f2[id] = s2; }
}

// ---------------------------------------------------------------------------
// K3: fused masked-softmax attention + PV, one pass (no max subtraction:
// masked entries are exactly 0, valid e is small enough for fp32 exp).
// Block = (64 rows of one head); K streamed in 64-wide chunks.
// out[n][h*64+o] = (sum_j p * Wh[h][j][o]) / (sum_j p),
//   p = adj[n][j] ? exp(leakyrelu(f1[h][n]+f2[h][j])) : 0
// ---------------------------------------------------------------------------
__global__ __launch_bounds__(256) void k3_attn(const int*   __restrict__ adj,
                                               const float* __restrict__ Wh,
                                               const float* __restrict__ f1,
                                               const float* __restrict__ f2,
                                               float* __restrict__ out) {
    __shared__ float ps[64][68];    // [jj][r]  P-tile (transposed)
    __shared__ float ws[64][68];    // [jj][o]  Wh-tile
    __shared__ float dred[64][4];   // denominator partials
    const int t    = threadIdx.x;
    const int h    = blockIdx.y;
    const int row0 = blockIdx.x * 64;
    const int pr   = t >> 2, psub = t & 3;   // p-phase: row, jj-group-of-16
    const int tr   = t >> 4, tc   = t & 15;  // gemm-phase thread grid 16x16
    const float* WH  = Wh + (size_t)h * NN * FOUT;
    const float  f1r = f1[h * NN + row0 + pr];
    const float* f2h = f2 + h * NN;
    float acc[4][4] = {};
    float dsum = 0.f;

    for (int jt = 0; jt < NN; jt += 64) {
        __syncthreads();   // previous GEMM done reading ps/ws
        // stage Wh tile: ws[k][o]
        #pragma unroll
        for (int i = 0; i < 4; ++i) {
            int idx = t + 256 * i;           // 0..1023
            int k = idx >> 4, o4 = idx & 15;
            *(float4*)&ws[k][o4*4] =
                *(const float4*)&WH[(size_t)(jt + k) * FOUT + o4*4];
        }
        // compute P-tile: each thread 16 entries of row pr
        const int*   arow = adj + (size_t)(row0 + pr) * NN + jt + psub * 16;
        const float* f2c  = f2h + jt + psub * 16;
        #pragma unroll 4
        for (int q = 0; q < 16; ++q) {
            float e = f1r + f2c[q];
            e = e > 0.f ? e : ALPHA * e;
            float p = (arow[q] > 0) ? __expf(e) : 0.f;
            ps[psub*16 + q][pr] = p;
            dsum += p;
        }
        __syncthreads();   // ps/ws visible
        // PV accumulate: acc[i][j] += ps[jj][tr*4+i] * ws[jj][tc*4+j]
        #pragma unroll 8
        for (int jj = 0; jj < 64; ++jj) {
            float4 a4 = *(const float4*)&ps[jj][tr*4];
            float4 b4 = *(const float4*)&ws[jj][tc*4];
            float a[4] = {a4.x, a4.y, a4.z, a4.w};
            float b[4] = {b4.x, b4.y, b4.z, b4.w};
            #pragma unroll
            for (int i = 0; i < 4; ++i)
                #pragma unroll
                for (int j = 0; j < 4; ++j)
                    acc[i][j] = fmaf(a[i], b[j], acc[i][j]);
        }
    }

    dred[pr][psub] = dsum;
    __syncthreads();
    #pragma unroll
    for (int i = 0; i < 4; ++i) {
        int r = tr*4 + i;
        float dn  = dred[r][0] + dred[r][1] + dred[r][2] + dred[r][3];
        float inv = 1.0f / dn;
        float4 v = {acc[i][0]*inv, acc[i][1]*inv, acc[i][2]*inv, acc[i][3]*inv};
        *(float4*)&out[(size_t)(row0 + r) * (NH*FOUT) + h*FOUT + tc*4] = v;
    }
}

extern "C" void kernel_launch(void* const* d_in, const int* in_sizes, int n_in,
                              void* d_out, int out_size, void* d_ws, size_t ws_size,
                              hipStream_t stream) {
    const float* x   = (const float*)d_in[0];
    const int*   adj = (const int*)d_in[1];
    const float* W   = (const float*)d_in[2];
    const float* a   = (const float*)d_in[3];
    float* outp = (float*)d_out;

    float* Wh = (float*)d_ws;                        // [NH][NN][FOUT] = 8 MB
    float* f1 = Wh + (size_t)NH * NN * FOUT;         // [NH][NN]
    float* f2 = f1 + NH * NN;                        // [NH][NN]

    k1_wh <<<dim3(NN/64, NH), 256, 0, stream>>>(x, W, Wh);
    k2_f12<<<dim3(NH*NN/4),   256, 0, stream>>>(Wh, a, f1, f2);
    k3_attn<<<dim3(NN/64, NH), 256, 0, stream>>>(adj, Wh, f1, f2, outp);
}

// Round 2
// 183.398 us; speedup vs baseline: 2.7147x; 2.7147x over previous
//
#include <hip/hip_runtime.h>

#define NN   4096
#define FIN  512
#define FOUT 64
#define NH   8
#define ALPHA 0.2f

typedef __attribute__((ext_vector_type(8))) short bf16x8;
typedef __attribute__((ext_vector_type(4))) float f32x4;

__device__ __forceinline__ unsigned short f2bf(float x) {
    unsigned u = __float_as_uint(x);
    unsigned r = (u + 0x7fffu + ((u >> 16) & 1u)) >> 16;   // RNE, x is finite/non-NaN
    return (unsigned short)r;
}

// ---------------------------------------------------------------------------
// K1: Wh[h][n][o] = sum_k x[n][k] * W[h][k][o]   (fp32, unchanged)
// ---------------------------------------------------------------------------
__global__ __launch_bounds__(256) void k1_wh(const float* __restrict__ x,
                                             const float* __restrict__ W,
                                             float* __restrict__ Wh) {
    __shared__ float As[16][68];
    __shared__ float Bs[16][68];
    const int t    = threadIdx.x;
    const int h    = blockIdx.y;
    const int row0 = blockIdx.x * 64;
    const int tr = t >> 4, tc = t & 15;
    const int ar = t >> 2, ak = t & 3;
    const int bk = t >> 4, bo = t & 15;
    const float* WH = W + (size_t)h * FIN * FOUT;
    float acc[4][4] = {};

    for (int k0 = 0; k0 < FIN; k0 += 16) {
        __syncthreads();
        float4 av = *(const float4*)&x[(size_t)(row0 + ar) * FIN + k0 + ak * 4];
        As[ak*4+0][ar] = av.x; As[ak*4+1][ar] = av.y;
        As[ak*4+2][ar] = av.z; As[ak*4+3][ar] = av.w;
        *(float4*)&Bs[bk][bo*4] =
            *(const float4*)&WH[(size_t)(k0 + bk) * FOUT + bo*4];
        __syncthreads();
        #pragma unroll
        for (int kk = 0; kk < 16; ++kk) {
            float4 a4 = *(const float4*)&As[kk][tr*4];
            float4 b4 = *(const float4*)&Bs[kk][tc*4];
            float a[4] = {a4.x, a4.y, a4.z, a4.w};
            float b[4] = {b4.x, b4.y, b4.z, b4.w};
            #pragma unroll
            for (int i = 0; i < 4; ++i)
                #pragma unroll
                for (int j = 0; j < 4; ++j)
                    acc[i][j] = fmaf(a[i], b[j], acc[i][j]);
        }
    }
    float* outp = Wh + (size_t)h * NN * FOUT;
    #pragma unroll
    for (int i = 0; i < 4; ++i) {
        float4 v = {acc[i][0], acc[i][1], acc[i][2], acc[i][3]};
        *(float4*)&outp[(size_t)(row0 + tr*4 + i) * FOUT + tc*4] = v;
    }
}

// ---------------------------------------------------------------------------
// K1T: WhT[h][o][n] = bf16(Wh[h][n][o])  — B-operand for k3's MFMA
// ---------------------------------------------------------------------------
__global__ __launch_bounds__(256) void k1t(const float* __restrict__ Wh,
                                           unsigned short* __restrict__ WhT) {
    __shared__ unsigned short T[64][72];
    const int t  = threadIdx.x;
    const int h  = blockIdx.y;
    const int n0 = blockIdx.x * 64;
    const float* src = Wh + ((size_t)h * NN + n0) * FOUT;
    const int r = t >> 2, oc = (t & 3) * 16;
    #pragma unroll
    for (int q = 0; q < 4; ++q) {
        float4 v = *(const float4*)&src[(size_t)r * FOUT + oc + q*4];
        T[oc+q*4+0][r] = f2bf(v.x);
        T[oc+q*4+1][r] = f2bf(v.y);
        T[oc+q*4+2][r] = f2bf(v.z);
        T[oc+q*4+3][r] = f2bf(v.w);
    }
    __syncthreads();
    #pragma unroll
    for (int i = 0; i < 2; ++i) {
        int c = t + i * 256;          // 512 chunks of 8 bf16
        int o = c >> 3, nch = c & 7;
        uint4 v = *(const uint4*)&T[o][nch * 8];
        *(uint4*)&WhT[((size_t)(h*64 + o)) * NN + n0 + nch * 8] = v;
    }
}

// ---------------------------------------------------------------------------
// K2: f1/f2 dot products (unchanged)
// ---------------------------------------------------------------------------
__global__ __launch_bounds__(256) void k2_f12(const float* __restrict__ Wh,
                                              const float* __restrict__ a,
                                              float* __restrict__ f1,
                                              float* __restrict__ f2) {
    const int id   = blockIdx.x * 4 + (threadIdx.x >> 6);
    const int lane = threadIdx.x & 63;
    const int h    = id >> 12;
    float v  = Wh[(size_t)id * FOUT + lane];
    float s1 = v * a[h * 2 * FOUT + lane];
    float s2 = v * a[h * 2 * FOUT + FOUT + lane];
    #pragma unroll
    for (int m = 32; m; m >>= 1) {
        s1 += __shfl_xor(s1, m);
        s2 += __shfl_xor(s2, m);
    }
    if (lane == 0) { f1[id] = s1; f2[id] = s2; }
}

// ---------------------------------------------------------------------------
// K3: fused masked softmax + PV via bf16 MFMA.
// Block: 64 rows of one head, 4 waves. Per 64-col tile:
//   phase A: all threads compute P (exp/mask) -> bf16 -> swizzled LDS,
//            stage WhT tile -> swizzled LDS
//   phase B: wave w rows 16w..16w+15; 4 col-frags x 2 k-steps of MFMA.
// Swizzle: row-major 64x128B, byte ^= (row&7)<<4  (conflict-free b128).
// ---------------------------------------------------------------------------
__global__ __launch_bounds__(256) void k3_attn(const int* __restrict__ adj,
        const unsigned short* __restrict__ WhT,
        const float* __restrict__ f1, const float* __restrict__ f2,
        float* __restrict__ out) {
    __shared__ unsigned char psB[64 * 128];
    __shared__ unsigned char wsB[64 * 128];
    __shared__ float dred[64][4];
    __shared__ float invden[64];
    const int t    = threadIdx.x;
    const int lane = t & 63, wid = t >> 6;
    const int h    = blockIdx.y;
    const int row0 = blockIdx.x * 64;
    const int pr   = t >> 2, psub = t & 3;
    const float f1r = f1[h * NN + row0 + pr];
    const float* f2h  = f2 + h * NN;
    const int*   adjr = adj + (size_t)(row0 + pr) * NN;
    const unsigned short* WT = WhT + (size_t)h * 64 * NN;
    f32x4 acc[4] = {};           // 4 col-frags for this wave's 16-row band
    float dsum = 0.f;

    for (int jt = 0; jt < NN; jt += 64) {
        __syncthreads();                       // MFMA of prev tile done
        // ---- stage B tile: wsB[o][jj] <- WT[o][jt+jj], swizzled ----
        #pragma unroll
        for (int i = 0; i < 2; ++i) {
            int c = t + i * 256;               // 512 x 16B chunks
            int o = c >> 3, kch = (c & 7) * 16;
            uint4 v = *(const uint4*)((const unsigned char*)(WT + (size_t)o * NN + jt) + kch);
            *(uint4*)&wsB[o * 128 + (kch ^ ((o & 7) << 4))] = v;
        }
        // ---- compute P: row pr, cols psub*16 .. +15 ----
        const int*   arow = adjr + jt + psub * 16;
        const float* f2c  = f2h  + jt + psub * 16;
        int   av[16]; float fv[16];
        #pragma unroll
        for (int i = 0; i < 4; ++i) {
            int4   a4 = *(const int4*)&arow[i*4];
            float4 f4 = *(const float4*)&f2c[i*4];
            av[i*4+0] = a4.x; av[i*4+1] = a4.y; av[i*4+2] = a4.z; av[i*4+3] = a4.w;
            fv[i*4+0] = f4.x; fv[i*4+1] = f4.y; fv[i*4+2] = f4.z; fv[i*4+3] = f4.w;
        }
        unsigned pk[8];
        #pragma unroll
        for (int q2 = 0; q2 < 8; ++q2) {
            float e0 = f1r + fv[2*q2+0];
            float e1 = f1r + fv[2*q2+1];
            e0 = e0 > 0.f ? e0 : ALPHA * e0;
            e1 = e1 > 0.f ? e1 : ALPHA * e1;
            float p0 = (av[2*q2+0] > 0) ? __expf(e0) : 0.f;
            float p1 = (av[2*q2+1] > 0) ? __expf(e1) : 0.f;
            dsum += p0 + p1;
            pk[q2] = (unsigned)f2bf(p0) | ((unsigned)f2bf(p1) << 16);
        }
        {
            uint4 w0 = {pk[0], pk[1], pk[2], pk[3]};
            uint4 w1 = {pk[4], pk[5], pk[6], pk[7]};
            int b0 = psub * 32;
            *(uint4*)&psB[pr * 128 + ((b0)      ^ ((pr & 7) << 4))] = w0;
            *(uint4*)&psB[pr * 128 + ((b0 + 16) ^ ((pr & 7) << 4))] = w1;
        }
        __syncthreads();                       // tiles visible
        // ---- MFMA ----
        const int arw = wid * 16 + (lane & 15);
        const int kb  = (lane >> 4) * 16;      // 16B chunk within 64B k-step
        #pragma unroll
        for (int ks = 0; ks < 2; ++ks) {
            bf16x8 af = *(const bf16x8*)&psB[arw * 128 + ((ks*64 + kb) ^ ((arw & 7) << 4))];
            #pragma unroll
            for (int cf = 0; cf < 4; ++cf) {
                int brw = cf * 16 + (lane & 15);
                bf16x8 bfr = *(const bf16x8*)&wsB[brw * 128 + ((ks*64 + kb) ^ ((brw & 7) << 4))];
                acc[cf] = __builtin_amdgcn_mfma_f32_16x16x32_bf16(af, bfr, acc[cf], 0, 0, 0);
            }
        }
    }

    dred[pr][psub] = dsum;
    __syncthreads();
    if (t < 64)
        invden[t] = 1.0f / (dred[t][0] + dred[t][1] + dred[t][2] + dred[t][3]);
    __syncthreads();

    // C/D: col = lane&15, row = (lane>>4)*4 + reg  (m89-verified)
    #pragma unroll
    for (int cf = 0; cf < 4; ++cf) {
        int o = cf * 16 + (lane & 15);
        #pragma unroll
        for (int rg = 0; rg < 4; ++rg) {
            int rl = wid * 16 + (lane >> 4) * 4 + rg;
            out[(size_t)(row0 + rl) * (NH * FOUT) + h * FOUT + o] = acc[cf][rg] * invden[rl];
        }
    }
}

extern "C" void kernel_launch(void* const* d_in, const int* in_sizes, int n_in,
                              void* d_out, int out_size, void* d_ws, size_t ws_size,
                              hipStream_t stream) {
    const float* x   = (const float*)d_in[0];
    const int*   adj = (const int*)d_in[1];
    const float* W   = (const float*)d_in[2];
    const float* a   = (const float*)d_in[3];
    float* outp = (float*)d_out;

    float* Wh = (float*)d_ws;                                   // 8 MB fp32
    float* f1 = Wh + (size_t)NH * NN * FOUT;                    // 128 KB
    float* f2 = f1 + NH * NN;
    unsigned short* WhT = (unsigned short*)(f2 + NH * NN);      // 4 MB bf16 [H][64][NN]

    k1_wh <<<dim3(NN/64, NH), 256, 0, stream>>>(x, W, Wh);
    k1t   <<<dim3(NN/64, NH), 256, 0, stream>>>(Wh, WhT);
    k2_f12<<<dim3(NH*NN/4),   256, 0, stream>>>(Wh, a, f1, f2);
    k3_attn<<<dim3(NN/64, NH), 256, 0, stream>>>(adj, WhT, f1, f2, outp);
}

// Round 3
// 162.343 us; speedup vs baseline: 3.0667x; 1.1297x over previous
//
#include <hip/hip_runtime.h>

#define NN   4096
#define FIN  512
#define FOUT 64
#define NH   8
#define ALPHA 0.2f

typedef __attribute__((ext_vector_type(8))) short bf16x8;
typedef __attribute__((ext_vector_type(4))) float f32x4;

__device__ __forceinline__ unsigned short f2bf(float x) {
    unsigned u = __float_as_uint(x);
    return (unsigned short)((u + 0x7fffu + ((u >> 16) & 1u)) >> 16);  // RNE
}

// ---------------------------------------------------------------------------
// K0 (merged): blocks [0, NBITBLK): adj -> 64-bit masks via ballot.
//              blocks [NBITBLK, +512): Wh GEMM + f1/f2 + bf16 WhT epilogue.
// ---------------------------------------------------------------------------
#define NBITBLK (NN * 64 / 4)   // 65536 blocks, 4 waves each, 1 mask per wave

__global__ __launch_bounds__(256) void k0(const float* __restrict__ x,
                                          const int*   __restrict__ adj,
                                          const float* __restrict__ W,
                                          const float* __restrict__ aw,
                                          unsigned long long* __restrict__ bits,
                                          unsigned short* __restrict__ WhT,
                                          float* __restrict__ f1,
                                          float* __restrict__ f2) {
    __shared__ float As[16][68];
    __shared__ float Bs[16][68];
    __shared__ unsigned short Tb[64][80];
    __shared__ float r1[64][16];
    __shared__ float r2[64][16];
    const int t = threadIdx.x;

    if (blockIdx.x < NBITBLK) {
        int id   = blockIdx.x * 4 + (t >> 6);
        int lane = t & 63;
        int row  = id >> 6, grp = id & 63;
        int v = adj[(size_t)row * NN + grp * 64 + lane];
        unsigned long long m = __ballot(v > 0);
        if (lane == 0) bits[(size_t)row * 64 + grp] = m;
        return;
    }

    const int bx   = blockIdx.x - NBITBLK;   // 0..511
    const int h    = bx >> 6;
    const int row0 = (bx & 63) * 64;
    const int tr = t >> 4, tc = t & 15;
    const int ar = t >> 2, ak = t & 3;
    const int bk = t >> 4, bo = t & 15;
    const float* WH = W + (size_t)h * FIN * FOUT;
    float acc[4][4] = {};

    for (int k0i = 0; k0i < FIN; k0i += 16) {
        __syncthreads();
        float4 av = *(const float4*)&x[(size_t)(row0 + ar) * FIN + k0i + ak * 4];
        As[ak*4+0][ar] = av.x; As[ak*4+1][ar] = av.y;
        As[ak*4+2][ar] = av.z; As[ak*4+3][ar] = av.w;
        *(float4*)&Bs[bk][bo*4] =
            *(const float4*)&WH[(size_t)(k0i + bk) * FOUT + bo*4];
        __syncthreads();
        #pragma unroll
        for (int kk = 0; kk < 16; ++kk) {
            float4 a4 = *(const float4*)&As[kk][tr*4];
            float4 b4 = *(const float4*)&Bs[kk][tc*4];
            float a[4] = {a4.x, a4.y, a4.z, a4.w};
            float b[4] = {b4.x, b4.y, b4.z, b4.w};
            #pragma unroll
            for (int i = 0; i < 4; ++i)
                #pragma unroll
                for (int j = 0; j < 4; ++j)
                    acc[i][j] = fmaf(a[i], b[j], acc[i][j]);
        }
    }

    // epilogue: f1/f2 partials + bf16 transpose tile
    float a1v[4], a2v[4];
    #pragma unroll
    for (int j = 0; j < 4; ++j) {
        a1v[j] = aw[h * 2 * FOUT + tc*4 + j];
        a2v[j] = aw[h * 2 * FOUT + FOUT + tc*4 + j];
    }
    #pragma unroll
    for (int i = 0; i < 4; ++i) {
        float s1 = 0.f, s2 = 0.f;
        #pragma unroll
        for (int j = 0; j < 4; ++j) {
            s1 = fmaf(acc[i][j], a1v[j], s1);
            s2 = fmaf(acc[i][j], a2v[j], s2);
            Tb[tc*4 + j][tr*4 + i] = f2bf(acc[i][j]);
        }
        r1[tr*4 + i][tc] = s1;
        r2[tr*4 + i][tc] = s2;
    }
    __syncthreads();
    if (t < 64) {
        float s1 = 0.f, s2 = 0.f;
        #pragma unroll
        for (int k = 0; k < 16; ++k) { s1 += r1[t][k]; s2 += r2[t][k]; }
        f1[h * NN + row0 + t] = s1;
        f2[h * NN + row0 + t] = s2;
    }
    #pragma unroll
    for (int i = 0; i < 2; ++i) {
        int c = t + i * 256;                 // 512 chunks of 8 bf16
        int o = c >> 3, nch = c & 7;
        *(uint4*)&WhT[((size_t)(h*64 + o)) * NN + row0 + nch*8] =
            *(const uint4*)&Tb[o][nch*8];
    }
}

// ---------------------------------------------------------------------------
// K3: fused masked softmax + PV (bf16 MFMA), j-split for occupancy.
// grid (NN/64, NH, JS); block = 64 rows, 4 waves, 16-row band per wave.
// Writes fp32 partial num [js][h][n][64] and den [js][h][n].
// ---------------------------------------------------------------------------
__global__ __launch_bounds__(256, 8) void k3_attn(
        const unsigned long long* __restrict__ bits,
        const unsigned short* __restrict__ WhT,
        const float* __restrict__ f1, const float* __restrict__ f2,
        float* __restrict__ pnum, float* __restrict__ pden) {
    __shared__ unsigned char psB[64 * 128];
    __shared__ unsigned char wsB[64 * 128];
    __shared__ float dred[64][4];
    const int t    = threadIdx.x;
    const int lane = t & 63, wid = t >> 6;
    const int h    = blockIdx.y;
    const int row0 = blockIdx.x * 64;
    const int js   = blockIdx.z, JS = gridDim.z;
    const int ntile = (NN / 64) / JS;
    const int j0    = js * ntile * 64;
    const int pr   = t >> 2, psub = t & 3;
    const float f1r = f1[h * NN + row0 + pr];
    const float* f2h = f2 + h * NN;
    const unsigned long long* bitsRow = bits + (size_t)(row0 + pr) * 64;
    const unsigned short* WT = WhT + (size_t)h * 64 * NN;
    const int prswz = (pr & 7) << 4;
    f32x4 acc[4] = {};
    float dsum = 0.f;

    for (int it = 0; it < ntile; ++it) {
        const int jt = j0 + it * 64;
        __syncthreads();                       // prev MFMA done with tiles
        // ---- stage Wh tile (swizzled) ----
        #pragma unroll
        for (int i = 0; i < 2; ++i) {
            int c = t + i * 256;
            int o = c >> 3, kch = (c & 7) * 16;
            uint4 v = *(const uint4*)((const unsigned char*)(WT + (size_t)o * NN + jt) + kch);
            *(uint4*)&wsB[o * 128 + (kch ^ ((o & 7) << 4))] = v;
        }
        // ---- compute P tile: row pr, 16 cols ----
        unsigned msk = (unsigned)(bitsRow[jt >> 6] >> (psub << 4)) & 0xFFFFu;
        const float* f2c = f2h + jt + psub * 16;
        #pragma unroll
        for (int half = 0; half < 2; ++half) {
            unsigned pk[4];
            #pragma unroll
            for (int c2 = 0; c2 < 2; ++c2) {
                const int c = half * 2 + c2;
                float4 f4 = *(const float4*)&f2c[c * 4];
                float e0 = f1r + f4.x, e1 = f1r + f4.y;
                float e2 = f1r + f4.z, e3 = f1r + f4.w;
                e0 = fmaxf(e0, ALPHA * e0); e1 = fmaxf(e1, ALPHA * e1);
                e2 = fmaxf(e2, ALPHA * e2); e3 = fmaxf(e3, ALPHA * e3);
                float p0 = ((msk >> (c*4+0)) & 1u) ? __expf(e0) : 0.f;
                float p1 = ((msk >> (c*4+1)) & 1u) ? __expf(e1) : 0.f;
                float p2 = ((msk >> (c*4+2)) & 1u) ? __expf(e2) : 0.f;
                float p3 = ((msk >> (c*4+3)) & 1u) ? __expf(e3) : 0.f;
                dsum += (p0 + p1) + (p2 + p3);
                pk[c2*2+0] = (unsigned)f2bf(p0) | ((unsigned)f2bf(p1) << 16);
                pk[c2*2+1] = (unsigned)f2bf(p2) | ((unsigned)f2bf(p3) << 16);
            }
            uint4 w = {pk[0], pk[1], pk[2], pk[3]};
            *(uint4*)&psB[pr * 128 + ((psub*32 + half*16) ^ prswz)] = w;
        }
        __syncthreads();                       // tiles visible
        // ---- MFMA ----
        const int arw = wid * 16 + (lane & 15);
        const int kb  = (lane >> 4) * 16;
        #pragma unroll
        for (int ks = 0; ks < 2; ++ks) {
            bf16x8 af = *(const bf16x8*)&psB[arw * 128 + ((ks*64 + kb) ^ ((arw & 7) << 4))];
            #pragma unroll
            for (int cf = 0; cf < 4; ++cf) {
                int brw = cf * 16 + (lane & 15);
                bf16x8 bfr = *(const bf16x8*)&wsB[brw * 128 + ((ks*64 + kb) ^ ((brw & 7) << 4))];
                acc[cf] = __builtin_amdgcn_mfma_f32_16x16x32_bf16(af, bfr, acc[cf], 0, 0, 0);
            }
        }
    }

    dred[pr][psub] = dsum;
    __syncthreads();

    float* pn = pnum + (((size_t)js * NH + h) * NN + row0) * 64;
    #pragma unroll
    for (int cf = 0; cf < 4; ++cf) {
        int o = cf * 16 + (lane & 15);
        #pragma unroll
        for (int rg = 0; rg < 4; ++rg) {
            int rl = wid * 16 + (lane >> 4) * 4 + rg;
            pn[(size_t)rl * 64 + o] = acc[cf][rg];
        }
    }
    if (t < 64)
        pden[((size_t)js * NH + h) * NN + row0 + t] =
            dred[t][0] + dred[t][1] + dred[t][2] + dred[t][3];
}

// ---------------------------------------------------------------------------
// K4: reduce over JS slices + normalize.  idx -> (h, n, o-quad)
// ---------------------------------------------------------------------------
__global__ __launch_bounds__(256) void k4_red(const float* __restrict__ pnum,
                                              const float* __restrict__ pden,
                                              float* __restrict__ out, int JS) {
    const int idx = blockIdx.x * 256 + threadIdx.x;   // 0..524287
    const int h   = idx >> 16;
    const int rem = idx & 65535;
    const int n   = rem >> 4;
    const int o4  = (rem & 15) * 4;
    float4 s = {0.f, 0.f, 0.f, 0.f};
    float  d = 0.f;
    for (int js = 0; js < JS; ++js) {
        const float* p = pnum + (((size_t)js * NH + h) * NN + n) * 64 + o4;
        float4 v = *(const float4*)p;
        s.x += v.x; s.y += v.y; s.z += v.z; s.w += v.w;
        d += pden[((size_t)js * NH + h) * NN + n];
    }
    float inv = 1.0f / d;
    float4 r = {s.x * inv, s.y * inv, s.z * inv, s.w * inv};
    *(float4*)&out[(size_t)n * (NH * FOUT) + h * FOUT + o4] = r;
}

extern "C" void kernel_launch(void* const* d_in, const int* in_sizes, int n_in,
                              void* d_out, int out_size, void* d_ws, size_t ws_size,
                              hipStream_t stream) {
    const float* x   = (const float*)d_in[0];
    const int*   adj = (const int*)d_in[1];
    const float* W   = (const float*)d_in[2];
    const float* a   = (const float*)d_in[3];
    float* outp = (float*)d_out;

    // workspace layout
    unsigned short* WhT = (unsigned short*)d_ws;                    // 4 MB
    float* f1 = (float*)(WhT + (size_t)NH * 64 * NN);               // 128 KB
    float* f2 = f1 + NH * NN;                                       // 128 KB
    unsigned long long* bits = (unsigned long long*)(f2 + NH * NN); // 2 MB
    float* pnum = (float*)(bits + (size_t)NN * 64);
    const size_t baseBytes  = (size_t)(pnum - (float*)d_ws) * 4;
    const size_t sliceBytes = (size_t)NH * NN * 65 * 4;             // num+den per slice
    int JS = 1;
    if (ws_size >= baseBytes + 4 * sliceBytes) JS = 4;
    else if (ws_size >= baseBytes + 2 * sliceBytes) JS = 2;
    float* pden = pnum + (size_t)JS * NH * NN * 64;

    k0     <<<dim3(NBITBLK + 512), 256, 0, stream>>>(x, adj, W, a, bits, WhT, f1, f2);
    k3_attn<<<dim3(NN/64, NH, JS), 256, 0, stream>>>(bits, WhT, f1, f2, pnum, pden);
    k4_red <<<dim3(NN*NH*FOUT/4/256), 256, 0, stream>>>(pnum, pden, outp, JS);
}

// Round 4
// 145.215 us; speedup vs baseline: 3.4284x; 1.1180x over previous
//
#include <hip/hip_runtime.h>

#define NN   4096
#define FIN  512
#define FOUT 64
#define NH   8
#define ALPHA 0.2f

typedef __attribute__((ext_vector_type(8))) short bf16x8;
typedef __attribute__((ext_vector_type(4))) float f32x4;

__device__ __forceinline__ unsigned short f2bf(float x) {
    unsigned u = __float_as_uint(x);
    return (unsigned short)((u + 0x7fffu + ((u >> 16) & 1u)) >> 16);  // RNE
}

// ---------------------------------------------------------------------------
// K0 (merged):
//   blocks [0, BITBLK):        adj -> 64-bit masks, grid-stride, ballot-free
//   blocks [BITBLK, +512):     Wh GEMM + f1/f2 + bf16 WhT epilogue
// ---------------------------------------------------------------------------
#define BITBLK 2048
#define NCHUNK (NN * NN / 256)   // 65536 chunks of 256 ints

__global__ __launch_bounds__(256) void k0(const float* __restrict__ x,
                                          const int*   __restrict__ adj,
                                          const float* __restrict__ W,
                                          const float* __restrict__ aw,
                                          unsigned long long* __restrict__ bits,
                                          unsigned short* __restrict__ WhT,
                                          float* __restrict__ f1,
                                          float* __restrict__ f2) {
    __shared__ float As[16][68];
    __shared__ float Bs[16][68];
    __shared__ unsigned short Tb[64][80];
    __shared__ float r1[64][16];
    __shared__ float r2[64][16];
    const int t = threadIdx.x;

    if (blockIdx.x < BITBLK) {
        const int wgl  = blockIdx.x * 4 + (t >> 6);   // 0..8191
        const int lane = t & 63;
        const int sh   = (lane & 15) * 4;
        const int grp  = lane >> 4;
        #pragma unroll
        for (int it = 0; it < NCHUNK / (BITBLK * 4); ++it) {
            const int c = wgl + it * (BITBLK * 4);
            int4 v = *(const int4*)(adj + (size_t)c * 256 + lane * 4);
            unsigned nib = (v.x > 0 ? 1u : 0u) | (v.y > 0 ? 2u : 0u)
                         | (v.z > 0 ? 4u : 0u) | (v.w > 0 ? 8u : 0u);
            unsigned long long part = (unsigned long long)nib << sh;
            part |= __shfl_xor(part, 1);
            part |= __shfl_xor(part, 2);
            part |= __shfl_xor(part, 4);
            part |= __shfl_xor(part, 8);
            if ((lane & 15) == 0) bits[(size_t)c * 4 + grp] = part;
        }
        return;
    }

    const int bx   = blockIdx.x - BITBLK;    // 0..511
    const int h    = bx >> 6;
    const int row0 = (bx & 63) * 64;
    const int tr = t >> 4, tc = t & 15;
    const int ar = t >> 2, ak = t & 3;
    const int bk = t >> 4, bo = t & 15;
    const float* WH = W + (size_t)h * FIN * FOUT;
    float acc[4][4] = {};

    for (int k0i = 0; k0i < FIN; k0i += 16) {
        __syncthreads();
        float4 av = *(const float4*)&x[(size_t)(row0 + ar) * FIN + k0i + ak * 4];
        As[ak*4+0][ar] = av.x; As[ak*4+1][ar] = av.y;
        As[ak*4+2][ar] = av.z; As[ak*4+3][ar] = av.w;
        *(float4*)&Bs[bk][bo*4] =
            *(const float4*)&WH[(size_t)(k0i + bk) * FOUT + bo*4];
        __syncthreads();
        #pragma unroll
        for (int kk = 0; kk < 16; ++kk) {
            float4 a4 = *(const float4*)&As[kk][tr*4];
            float4 b4 = *(const float4*)&Bs[kk][tc*4];
            float a[4] = {a4.x, a4.y, a4.z, a4.w};
            float b[4] = {b4.x, b4.y, b4.z, b4.w};
            #pragma unroll
            for (int i = 0; i < 4; ++i)
                #pragma unroll
                for (int j = 0; j < 4; ++j)
                    acc[i][j] = fmaf(a[i], b[j], acc[i][j]);
        }
    }

    // epilogue: f1/f2 partials + bf16 transpose tile
    float a1v[4], a2v[4];
    #pragma unroll
    for (int j = 0; j < 4; ++j) {
        a1v[j] = aw[h * 2 * FOUT + tc*4 + j];
        a2v[j] = aw[h * 2 * FOUT + FOUT + tc*4 + j];
    }
    #pragma unroll
    for (int i = 0; i < 4; ++i) {
        float s1 = 0.f, s2 = 0.f;
        #pragma unroll
        for (int j = 0; j < 4; ++j) {
            s1 = fmaf(acc[i][j], a1v[j], s1);
            s2 = fmaf(acc[i][j], a2v[j], s2);
            Tb[tc*4 + j][tr*4 + i] = f2bf(acc[i][j]);
        }
        r1[tr*4 + i][tc] = s1;
        r2[tr*4 + i][tc] = s2;
    }
    __syncthreads();
    if (t < 64) {
        float s1 = 0.f, s2 = 0.f;
        #pragma unroll
        for (int k = 0; k < 16; ++k) { s1 += r1[t][k]; s2 += r2[t][k]; }
        f1[h * NN + row0 + t] = s1;
        f2[h * NN + row0 + t] = s2;
    }
    #pragma unroll
    for (int i = 0; i < 2; ++i) {
        int c = t + i * 256;                 // 512 chunks of 8 bf16
        int o = c >> 3, nch = c & 7;
        *(uint4*)&WhT[((size_t)(h*64 + o)) * NN + row0 + nch*8] =
            *(const uint4*)&Tb[o][nch*8];
    }
}

// ---------------------------------------------------------------------------
// K3: fused masked softmax + PV (bf16 MFMA), j-split for occupancy.
// grid (NN/64, NH, JS); block = 64 rows, 4 waves, 16-row band per wave.
// Writes fp32 partial num [js][h][n][64] and den [js][h][n].
// ---------------------------------------------------------------------------
__global__ __launch_bounds__(256, 8) void k3_attn(
        const unsigned long long* __restrict__ bits,
        const unsigned short* __restrict__ WhT,
        const float* __restrict__ f1, const float* __restrict__ f2,
        float* __restrict__ pnum, float* __restrict__ pden) {
    __shared__ unsigned char psB[64 * 128];
    __shared__ unsigned char wsB[64 * 128];
    __shared__ float dred[64][4];
    const int t    = threadIdx.x;
    const int lane = t & 63, wid = t >> 6;
    const int h    = blockIdx.y;
    const int row0 = blockIdx.x * 64;
    const int js   = blockIdx.z, JS = gridDim.z;
    const int ntile = (NN / 64) / JS;
    const int j0    = js * ntile * 64;
    const int pr   = t >> 2, psub = t & 3;
    const float f1r = f1[h * NN + row0 + pr];
    const float* f2h = f2 + h * NN;
    const unsigned long long* bitsRow = bits + (size_t)(row0 + pr) * 64;
    const unsigned short* WT = WhT + (size_t)h * 64 * NN;
    const int prswz = (pr & 7) << 4;
    f32x4 acc[4] = {};
    float dsum = 0.f;

    for (int it = 0; it < ntile; ++it) {
        const int jt = j0 + it * 64;
        __syncthreads();                       // prev MFMA done with tiles
        // ---- stage Wh tile (swizzled) ----
        #pragma unroll
        for (int i = 0; i < 2; ++i) {
            int c = t + i * 256;
            int o = c >> 3, kch = (c & 7) * 16;
            uint4 v = *(const uint4*)((const unsigned char*)(WT + (size_t)o * NN + jt) + kch);
            *(uint4*)&wsB[o * 128 + (kch ^ ((o & 7) << 4))] = v;
        }
        // ---- compute P tile: row pr, 16 cols ----
        unsigned msk = (unsigned)(bitsRow[jt >> 6] >> (psub << 4)) & 0xFFFFu;
        const float* f2c = f2h + jt + psub * 16;
        #pragma unroll
        for (int half = 0; half < 2; ++half) {
            unsigned pk[4];
            #pragma unroll
            for (int c2 = 0; c2 < 2; ++c2) {
                const int c = half * 2 + c2;
                float4 f4 = *(const float4*)&f2c[c * 4];
                float e0 = f1r + f4.x, e1 = f1r + f4.y;
                float e2 = f1r + f4.z, e3 = f1r + f4.w;
                e0 = fmaxf(e0, ALPHA * e0); e1 = fmaxf(e1, ALPHA * e1);
                e2 = fmaxf(e2, ALPHA * e2); e3 = fmaxf(e3, ALPHA * e3);
                float p0 = ((msk >> (c*4+0)) & 1u) ? __expf(e0) : 0.f;
                float p1 = ((msk >> (c*4+1)) & 1u) ? __expf(e1) : 0.f;
                float p2 = ((msk >> (c*4+2)) & 1u) ? __expf(e2) : 0.f;
                float p3 = ((msk >> (c*4+3)) & 1u) ? __expf(e3) : 0.f;
                dsum += (p0 + p1) + (p2 + p3);
                pk[c2*2+0] = (unsigned)f2bf(p0) | ((unsigned)f2bf(p1) << 16);
                pk[c2*2+1] = (unsigned)f2bf(p2) | ((unsigned)f2bf(p3) << 16);
            }
            uint4 w = {pk[0], pk[1], pk[2], pk[3]};
            *(uint4*)&psB[pr * 128 + ((psub*32 + half*16) ^ prswz)] = w;
        }
        __syncthreads();                       // tiles visible
        // ---- MFMA ----
        const int arw = wid * 16 + (lane & 15);
        const int kb  = (lane >> 4) * 16;
        #pragma unroll
        for (int ks = 0; ks < 2; ++ks) {
            bf16x8 af = *(const bf16x8*)&psB[arw * 128 + ((ks*64 + kb) ^ ((arw & 7) << 4))];
            #pragma unroll
            for (int cf = 0; cf < 4; ++cf) {
                int brw = cf * 16 + (lane & 15);
                bf16x8 bfr = *(const bf16x8*)&wsB[brw * 128 + ((ks*64 + kb) ^ ((brw & 7) << 4))];
                acc[cf] = __builtin_amdgcn_mfma_f32_16x16x32_bf16(af, bfr, acc[cf], 0, 0, 0);
            }
        }
    }

    dred[pr][psub] = dsum;
    __syncthreads();

    float* pn = pnum + (((size_t)js * NH + h) * NN + row0) * 64;
    #pragma unroll
    for (int cf = 0; cf < 4; ++cf) {
        int o = cf * 16 + (lane & 15);
        #pragma unroll
        for (int rg = 0; rg < 4; ++rg) {
            int rl = wid * 16 + (lane >> 4) * 4 + rg;
            pn[(size_t)rl * 64 + o] = acc[cf][rg];
        }
    }
    if (t < 64)
        pden[((size_t)js * NH + h) * NN + row0 + t] =
            dred[t][0] + dred[t][1] + dred[t][2] + dred[t][3];
}

// ---------------------------------------------------------------------------
// K4: reduce over JS slices + normalize.  idx -> (h, n, o-quad)
// ---------------------------------------------------------------------------
__global__ __launch_bounds__(256) void k4_red(const float* __restrict__ pnum,
                                              const float* __restrict__ pden,
                                              float* __restrict__ out, int JS) {
    const int idx = blockIdx.x * 256 + threadIdx.x;   // 0..524287
    const int h   = idx >> 16;
    const int rem = idx & 65535;
    const int n   = rem >> 4;
    const int o4  = (rem & 15) * 4;
    float4 s = {0.f, 0.f, 0.f, 0.f};
    float  d = 0.f;
    for (int js = 0; js < JS; ++js) {
        const float* p = pnum + (((size_t)js * NH + h) * NN + n) * 64 + o4;
        float4 v = *(const float4*)p;
        s.x += v.x; s.y += v.y; s.z += v.z; s.w += v.w;
        d += pden[((size_t)js * NH + h) * NN + n];
    }
    float inv = 1.0f / d;
    float4 r = {s.x * inv, s.y * inv, s.z * inv, s.w * inv};
    *(float4*)&out[(size_t)n * (NH * FOUT) + h * FOUT + o4] = r;
}

extern "C" void kernel_launch(void* const* d_in, const int* in_sizes, int n_in,
                              void* d_out, int out_size, void* d_ws, size_t ws_size,
                              hipStream_t stream) {
    const float* x   = (const float*)d_in[0];
    const int*   adj = (const int*)d_in[1];
    const float* W   = (const float*)d_in[2];
    const float* a   = (const float*)d_in[3];
    float* outp = (float*)d_out;

    // workspace layout
    unsigned short* WhT = (unsigned short*)d_ws;                    // 4 MB
    float* f1 = (float*)(WhT + (size_t)NH * 64 * NN);               // 128 KB
    float* f2 = f1 + NH * NN;                                       // 128 KB
    unsigned long long* bits = (unsigned long long*)(f2 + NH * NN); // 2 MB
    float* pnum = (float*)(bits + (size_t)NN * 64);
    const size_t baseBytes  = (size_t)(pnum - (float*)d_ws) * 4;
    const size_t sliceBytes = (size_t)NH * NN * 65 * 4;             // num+den per slice
    int JS = 1;
    if (ws_size >= baseBytes + 4 * sliceBytes) JS = 4;
    else if (ws_size >= baseBytes + 2 * sliceBytes) JS = 2;
    float* pden = pnum + (size_t)JS * NH * NN * 64;

    k0     <<<dim3(BITBLK + 512), 256, 0, stream>>>(x, adj, W, a, bits, WhT, f1, f2);
    k3_attn<<<dim3(NN/64, NH, JS), 256, 0, stream>>>(bits, WhT, f1, f2, pnum, pden);
    k4_red <<<dim3(NN*NH*FOUT/4/256), 256, 0, stream>>>(pnum, pden, outp, JS);
}